// Round 8
// baseline (355.306 us; speedup 1.0000x reference)
//
#include <hip/hip_runtime.h>
#include <hip/hip_bf16.h>
#include <cstdint>

#define B_ 16
#define N_ 2048
#define D_ 64

typedef __bf16 bf16x8_t __attribute__((ext_vector_type(8)));
typedef __bf16 bf16x4_t __attribute__((ext_vector_type(4)));
typedef float f32x4_t __attribute__((ext_vector_type(4)));
typedef int   int4_t  __attribute__((ext_vector_type(4)));

// K1 LDS map (round-7 layout minus Et/Rinv):
#define KSTR 136
#define KHI  0
#define KLO  17408
#define V0B  34816
#define V1B  52224
#define MB_  69632
#define MSTR 132
#define LBB  71744
#define LDSZ (LBB + 512)

__device__ __forceinline__ void split8r(const f32x4_t a, const f32x4_t bq, bf16x8_t& h, bf16x8_t& lo) {
    #pragma unroll
    for (int j = 0; j < 4; ++j) {
        __bf16 h0 = (__bf16)a[j];
        h[j] = h0;     lo[j]     = (__bf16)(a[j]  - (float)h0);
        __bf16 h1 = (__bf16)bq[j];
        h[4 + j] = h1; lo[4 + j] = (__bf16)(bq[j] - (float)h1);
    }
}
__device__ __forceinline__ void split4r(const f32x4_t a, bf16x4_t& h, bf16x4_t& lo) {
    #pragma unroll
    for (int j = 0; j < 4; ++j) {
        __bf16 h0 = (__bf16)a[j];
        h[j] = h0;  lo[j] = (__bf16)(a[j] - (float)h0);
    }
}
__device__ __forceinline__ bf16x8_t lds_read8(const char* p) {
    bf16x4_t a = *(const bf16x4_t*)(p);
    bf16x4_t b = *(const bf16x4_t*)(p + 8);
    return __builtin_shufflevector(a, b, 0, 1, 2, 3, 4, 5, 6, 7);
}

// ============ K1: QK^T + mask + exp -> E(bf16 plane in out1), raw sums -> ws, O_unnorm -> out0 ============
__global__ __launch_bounds__(512, 4)
void attn_k1(const float* __restrict__ qg,
             const float* __restrict__ kg,
             const float* __restrict__ vg,
             const int*   __restrict__ mg,
             float* __restrict__ out0,
             float* __restrict__ out1,
             float* __restrict__ sums)
{
    __shared__ __align__(16) char lds[LDSZ];

    const int tid = threadIdx.x;
    const int w = tid >> 6, l = tid & 63, g = l >> 4, c = l & 15;

    const int bid = ((int)blockIdx.x & 7) * 256 + ((int)blockIdx.x >> 3);
    const int b  = bid >> 7;
    const int m0 = (bid & 127) << 4;

    bf16x8_t qh0, ql0, qh1, ql1;
    {
        const float* qrow = qg + ((size_t)(b * N_ + m0 + c)) * D_ + g * 8;
        split8r(*(const f32x4_t*)qrow, *(const f32x4_t*)(qrow + 4), qh0, ql0);
        split8r(*(const f32x4_t*)(qrow + 32), *(const f32x4_t*)(qrow + 36), qh1, ql1);
    }

    const int krow_ = tid >> 4;
    const int kcol_ = (tid & 15) * 4;
    const int mrow_ = tid >> 5;
    const int mcol_ = (tid & 31) * 4;
    const int* mgrow = mg + (size_t)(b * N_ + m0 + mrow_) * N_ + mcol_;

    float lsum = 0.f;
    f32x4_t of[4] = {};
    bf16x4_t paE[16];

    f32x4_t kin[4], vin[4]; int4_t min_;
    #pragma unroll
    for (int u = 0; u < 4; ++u) {
        const size_t roff = ((size_t)(b * N_ + krow_ + 32 * u)) * D_ + kcol_;
        kin[u] = *(const f32x4_t*)(kg + roff);
        vin[u] = *(const f32x4_t*)(vg + roff);
    }
    min_ = *(const int4_t*)(mgrow);

    #pragma unroll
    for (int p = 0; p < 8; ++p) {
        #pragma unroll
        for (int h = 0; h < 2; ++h) {
            const int nhalf = p * 256 + h * 128;
            const int vbase = h ? V1B : V0B;

            #pragma unroll
            for (int u = 0; u < 4; ++u) {
                const int row = krow_ + 32 * u;
                bf16x4_t kh, klo;
                split4r(kin[u], kh, klo);
                *(bf16x4_t*)(lds + KHI + row * KSTR + kcol_ * 2) = kh;
                *(bf16x4_t*)(lds + KLO + row * KSTR + kcol_ * 2) = klo;
                bf16x4_t v4;
                #pragma unroll
                for (int j = 0; j < 4; ++j) v4[j] = (__bf16)vin[u][j];
                *(bf16x4_t*)(lds + vbase + row * KSTR + kcol_ * 2) = v4;
            }
            {
                unsigned mbytes = 0;
                #pragma unroll
                for (int j = 0; j < 4; ++j) mbytes |= (min_[j] ? 1u : 0u) << (8 * j);
                *(unsigned*)(lds + MB_ + mrow_ * MSTR + mcol_) = mbytes;
            }

            if ((p < 7) || (h < 1)) {
                const int nnext = nhalf + 128;
                #pragma unroll
                for (int u = 0; u < 4; ++u) {
                    const size_t roff = ((size_t)(b * N_ + nnext + krow_ + 32 * u)) * D_ + kcol_;
                    kin[u] = *(const f32x4_t*)(kg + roff);
                    vin[u] = *(const f32x4_t*)(vg + roff);
                }
                min_ = *(const int4_t*)(mgrow + nnext);
            }
            __syncthreads();

            bf16x4_t pe;
            {
                const char* ka = lds + KHI + (16 * w + c) * KSTR + g * 16;
                const char* la = lds + KLO + (16 * w + c) * KSTR + g * 16;
                bf16x8_t ka0 = lds_read8(ka);
                bf16x8_t ka1 = lds_read8(ka + 64);
                bf16x8_t la0 = lds_read8(la);
                bf16x8_t la1 = lds_read8(la + 64);
                f32x4_t acc = {0.f, 0.f, 0.f, 0.f};
                acc = __builtin_amdgcn_mfma_f32_16x16x32_bf16(ka0, qh0, acc, 0, 0, 0);
                acc = __builtin_amdgcn_mfma_f32_16x16x32_bf16(ka1, qh1, acc, 0, 0, 0);
                acc = __builtin_amdgcn_mfma_f32_16x16x32_bf16(la0, qh0, acc, 0, 0, 0);
                acc = __builtin_amdgcn_mfma_f32_16x16x32_bf16(la1, qh1, acc, 0, 0, 0);
                acc = __builtin_amdgcn_mfma_f32_16x16x32_bf16(ka0, ql0, acc, 0, 0, 0);
                acc = __builtin_amdgcn_mfma_f32_16x16x32_bf16(ka1, ql1, acc, 0, 0, 0);
                const unsigned mu = *(const unsigned*)(lds + MB_ + c * MSTR + 16 * w + 4 * g);
                #pragma unroll
                for (int r = 0; r < 4; ++r) {
                    float e = ((mu >> (8 * r)) & 255u) ? 0.f : __expf(acc[r]);
                    lsum += e;
                    pe[r] = (__bf16)e;
                }
            }
            paE[2 * p + h] = pe;

            if (h == 0) {
                __syncthreads();
            } else {
                bf16x8_t pa8 = __builtin_shufflevector(paE[2 * p], paE[2 * p + 1],
                                                       0, 1, 2, 3, 4, 5, 6, 7);
                #pragma unroll
                for (int t = 0; t < 4; ++t) {
                    bf16x8_t vbf;
                    #pragma unroll
                    for (int j = 0; j < 4; ++j) {
                        const int rr = 16 * w + 4 * g + j;
                        vbf[j]     = *(const __bf16*)(lds + V0B + rr * KSTR + (16 * t + c) * 2);
                        vbf[4 + j] = *(const __bf16*)(lds + V1B + rr * KSTR + (16 * t + c) * 2);
                    }
                    of[t] = __builtin_amdgcn_mfma_f32_16x16x32_bf16(pa8, vbf, of[t], 0, 0, 0);
                }
                __syncthreads();
            }
        }
    }

    // ---- epilogue: E bf16 plane (block-private back half of own out1 tile) ----
    {
        char* Ep = (char*)out1 + ((size_t)(b * N_ + m0)) * N_ * 4 + 65536
                 + (size_t)c * 4096 + 32 * w;
        #pragma unroll
        for (int u = 0; u < 16; ++u)
            *(bf16x4_t*)(Ep + u * 256 + g * 8) = paE[u];   // E[m=c][u*128+16w+4g+r]
    }

    // O partials into (dead) K region + raw row-sums
    {
        float* Ow = (float*)(lds + w * 4096);
        #pragma unroll
        for (int t = 0; t < 4; ++t)
            #pragma unroll
            for (int r = 0; r < 4; ++r)
                Ow[(g * 4 + r) * 64 + t * 16 + c] = of[t][r];
    }
    lsum += __shfl_xor(lsum, 16);
    lsum += __shfl_xor(lsum, 32);
    float* Lbuf = (float*)(lds + LBB);
    if (l < 16) Lbuf[w * 16 + l] = lsum;
    __syncthreads();

    if (tid < 16) {
        float s = 0.f;
        #pragma unroll
        for (int ww = 0; ww < 8; ++ww) s += Lbuf[ww * 16 + tid];
        sums[(size_t)bid * 16 + tid] = s;
    }

    if (tid < 256) {
        const int row = tid >> 4;
        const int dc  = (tid & 15) * 4;
        f32x4_t o = {0.f, 0.f, 0.f, 0.f};
        #pragma unroll
        for (int ww = 0; ww < 8; ++ww)
            o += *(const f32x4_t*)((const float*)(lds + ww * 4096) + row * 64 + dc);
        *(f32x4_t*)(out0 + ((size_t)(b * N_ + m0 + row)) * D_ + dc) = o;   // unnormalized
    }
}

// ============ K3: out1 = E * rinv (fp32, streaming), out0 *= rinv in place ============
__global__ __launch_bounds__(512, 4)
void attn_k3(const float* __restrict__ sums,
             float* __restrict__ out0,
             float* __restrict__ out1)
{
    const int tid = threadIdx.x;
    const int bid = (int)blockIdx.x;          // b*128 + mtile
    const int b  = bid >> 7;
    const int m0 = (bid & 127) << 4;
    const size_t tb = ((size_t)(b * N_ + m0)) * N_;   // f32 index of tile base

    const int row = tid >> 5;                 // 0..15
    const int ch  = tid & 31;                 // 64-float chunk
    const float ri = 1.0f / sums[(size_t)bid * 16 + row];

    // load this thread's 64 bf16 E values fully into regs (E plane = 2nd half of tile)
    const char* esrc = (const char*)out1 + tb * 4 + 65536 + (size_t)row * 4096 + ch * 128;
    bf16x8_t e[8];
    #pragma unroll
    for (int i = 0; i < 8; ++i) e[i] = *(const bf16x8_t*)(esrc + i * 16);
    __syncthreads();                          // all E read before any fp32 overwrite

    float* dst = out1 + tb + (size_t)row * N_ + ch * 64;
    #pragma unroll
    for (int i = 0; i < 8; ++i) {
        f32x4_t o0, o1;
        #pragma unroll
        for (int j = 0; j < 4; ++j) {
            o0[j] = (float)e[i][j]     * ri;
            o1[j] = (float)e[i][4 + j] * ri;
        }
        *(f32x4_t*)(dst + i * 8)     = o0;
        *(f32x4_t*)(dst + i * 8 + 4) = o1;
    }

    if (tid < 256) {
        const int r2 = tid >> 4;
        const int dc = (tid & 15) * 4;
        const float ri2 = 1.0f / sums[(size_t)bid * 16 + r2];
        float* p = out0 + ((size_t)(b * N_ + m0 + r2)) * D_ + dc;
        f32x4_t o = *(const f32x4_t*)p;
        o.x *= ri2; o.y *= ri2; o.z *= ri2; o.w *= ri2;
        *(f32x4_t*)p = o;
    }
}

extern "C" void kernel_launch(void* const* d_in, const int* in_sizes, int n_in,
                              void* d_out, int out_size, void* d_ws, size_t ws_size,
                              hipStream_t stream) {
    (void)in_sizes; (void)n_in; (void)out_size; (void)ws_size;
    const float* q = (const float*)d_in[0];
    const float* k = (const float*)d_in[1];
    const float* v = (const float*)d_in[2];
    const int* mask = (const int*)d_in[3];
    float* out0 = (float*)d_out;                          // [B,N,D]
    float* out1 = out0 + (size_t)B_ * N_ * D_;            // [B,N,N]
    float* sums = (float*)d_ws;                           // 2048*16 f32 = 128KB
    attn_k1<<<dim3(B_ * (N_ / 16)), dim3(512), 0, stream>>>(q, k, v, mask, out0, out1, sums);
    attn_k3<<<dim3(B_ * (N_ / 16)), dim3(512), 0, stream>>>(sums, out0, out1);
}

// Round 9
// 322.762 us; speedup vs baseline: 1.1008x; 1.1008x over previous
//
#include <hip/hip_runtime.h>
#include <hip/hip_bf16.h>
#include <cstdint>

#define B_ 16
#define N_ 2048
#define D_ 64

typedef __bf16 bf16x8_t __attribute__((ext_vector_type(8)));
typedef __bf16 bf16x4_t __attribute__((ext_vector_type(4)));
typedef float f32x4_t __attribute__((ext_vector_type(4)));
typedef int   int4_t  __attribute__((ext_vector_type(4)));

// K1 LDS map:
#define KSTR 136
#define KHI  0
#define KLO  17408
#define V0B  34816
#define V1B  52224
#define MB_  69632
#define MSTR 132
#define ETB  71744
#define LBB  76864
#define LDSZ (LBB + 512)

__device__ __forceinline__ void split8r(const f32x4_t a, const f32x4_t bq, bf16x8_t& h, bf16x8_t& lo) {
    #pragma unroll
    for (int j = 0; j < 4; ++j) {
        __bf16 h0 = (__bf16)a[j];
        h[j] = h0;     lo[j]     = (__bf16)(a[j]  - (float)h0);
        __bf16 h1 = (__bf16)bq[j];
        h[4 + j] = h1; lo[4 + j] = (__bf16)(bq[j] - (float)h1);
    }
}
__device__ __forceinline__ void split4r(const f32x4_t a, bf16x4_t& h, bf16x4_t& lo) {
    #pragma unroll
    for (int j = 0; j < 4; ++j) {
        __bf16 h0 = (__bf16)a[j];
        h[j] = h0;  lo[j] = (__bf16)(a[j] - (float)h0);
    }
}
__device__ __forceinline__ bf16x8_t lds_read8(const char* p) {
    bf16x4_t a = *(const bf16x4_t*)(p);
    bf16x4_t b = *(const bf16x4_t*)(p + 8);
    return __builtin_shufflevector(a, b, 0, 1, 2, 3, 4, 5, 6, 7);
}

// ============ K1: QK^T + mask + exp -> E plane (streamed per-half), sums -> ws, O_unnorm -> out0 ============
__global__ __launch_bounds__(512, 4)
void attn_k1(const float* __restrict__ qg,
             const float* __restrict__ kg,
             const float* __restrict__ vg,
             const int*   __restrict__ mg,
             float* __restrict__ out0,
             float* __restrict__ out1,
             float* __restrict__ sums)
{
    __shared__ __align__(16) char lds[LDSZ];

    const int tid = threadIdx.x;
    const int w = tid >> 6, l = tid & 63, g = l >> 4, c = l & 15;

    const int bid = ((int)blockIdx.x & 7) * 256 + ((int)blockIdx.x >> 3);
    const int b  = bid >> 7;
    const int m0 = (bid & 127) << 4;

    bf16x8_t qh0, ql0, qh1, ql1;
    {
        const float* qrow = qg + ((size_t)(b * N_ + m0 + c)) * D_ + g * 8;
        split8r(*(const f32x4_t*)qrow, *(const f32x4_t*)(qrow + 4), qh0, ql0);
        split8r(*(const f32x4_t*)(qrow + 32), *(const f32x4_t*)(qrow + 36), qh1, ql1);
    }

    const int krow_ = tid >> 4;
    const int kcol_ = (tid & 15) * 4;
    const int mrow_ = tid >> 5;
    const int mcol_ = (tid & 31) * 4;
    const int* mgrow = mg + (size_t)(b * N_ + m0 + mrow_) * N_ + mcol_;

    // per-wave Et bounce (wave-private), E-plane pointers
    char* Et = lds + ETB + w * 640;            // [16][20] bf16
    const int rm = l >> 2, kq = l & 3;
    char* Eplane = (char*)out1 + ((size_t)(b * N_ + m0)) * N_ * 4 + 65536;

    float lsum = 0.f;
    f32x4_t of[4] = {};
    bf16x4_t peh0 = {};                        // h==0's pe, paired into PV at h==1

    f32x4_t kin[4], vin[4]; int4_t min_;
    #pragma unroll
    for (int u = 0; u < 4; ++u) {
        const size_t roff = ((size_t)(b * N_ + krow_ + 32 * u)) * D_ + kcol_;
        kin[u] = *(const f32x4_t*)(kg + roff);
        vin[u] = *(const f32x4_t*)(vg + roff);
    }
    min_ = *(const int4_t*)(mgrow);

    #pragma unroll 1
    for (int p = 0; p < 8; ++p) {
        #pragma unroll
        for (int h = 0; h < 2; ++h) {
            const int nhalf = p * 256 + h * 128;
            const int vbase = h ? V1B : V0B;

            // ---- 1. stage current half (from prefetched regs) ----
            #pragma unroll
            for (int u = 0; u < 4; ++u) {
                const int row = krow_ + 32 * u;
                bf16x4_t kh, klo;
                split4r(kin[u], kh, klo);
                *(bf16x4_t*)(lds + KHI + row * KSTR + kcol_ * 2) = kh;
                *(bf16x4_t*)(lds + KLO + row * KSTR + kcol_ * 2) = klo;
                bf16x4_t v4;
                #pragma unroll
                for (int j = 0; j < 4; ++j) v4[j] = (__bf16)vin[u][j];
                *(bf16x4_t*)(lds + vbase + row * KSTR + kcol_ * 2) = v4;
            }
            {
                unsigned mbytes = 0;
                #pragma unroll
                for (int j = 0; j < 4; ++j) mbytes |= (min_[j] ? 1u : 0u) << (8 * j);
                *(unsigned*)(lds + MB_ + mrow_ * MSTR + mcol_) = mbytes;
            }
            __syncthreads();

            // ---- 2. issue next-half loads AFTER the barrier (full compute phase of cover) ----
            if ((p < 7) || (h < 1)) {
                const int nnext = nhalf + 128;
                #pragma unroll
                for (int u = 0; u < 4; ++u) {
                    const size_t roff = ((size_t)(b * N_ + nnext + krow_ + 32 * u)) * D_ + kcol_;
                    kin[u] = *(const f32x4_t*)(kg + roff);
                    vin[u] = *(const f32x4_t*)(vg + roff);
                }
                min_ = *(const int4_t*)(mgrow + nnext);
            }

            // ---- 3. QK^T (swapped) on this wave's 16-n band, mask, exp ----
            bf16x4_t pe;
            {
                const char* ka = lds + KHI + (16 * w + c) * KSTR + g * 16;
                const char* la = lds + KLO + (16 * w + c) * KSTR + g * 16;
                bf16x8_t ka0 = lds_read8(ka);
                bf16x8_t ka1 = lds_read8(ka + 64);
                bf16x8_t la0 = lds_read8(la);
                bf16x8_t la1 = lds_read8(la + 64);
                f32x4_t acc = {0.f, 0.f, 0.f, 0.f};
                acc = __builtin_amdgcn_mfma_f32_16x16x32_bf16(ka0, qh0, acc, 0, 0, 0);
                acc = __builtin_amdgcn_mfma_f32_16x16x32_bf16(ka1, qh1, acc, 0, 0, 0);
                acc = __builtin_amdgcn_mfma_f32_16x16x32_bf16(la0, qh0, acc, 0, 0, 0);
                acc = __builtin_amdgcn_mfma_f32_16x16x32_bf16(la1, qh1, acc, 0, 0, 0);
                acc = __builtin_amdgcn_mfma_f32_16x16x32_bf16(ka0, ql0, acc, 0, 0, 0);
                acc = __builtin_amdgcn_mfma_f32_16x16x32_bf16(ka1, ql1, acc, 0, 0, 0);
                const unsigned mu = *(const unsigned*)(lds + MB_ + c * MSTR + 16 * w + 4 * g);
                #pragma unroll
                for (int r = 0; r < 4; ++r) {
                    float e = ((mu >> (8 * r)) & 255u) ? 0.f : __expf(acc[r]);
                    lsum += e;
                    pe[r] = (__bf16)e;
                }
            }

            // ---- 4. stream E out via wave-private Et bounce (no block barrier) ----
            *(bf16x4_t*)(Et + c * 40 + g * 8) = pe;
            {
                bf16x4_t er = *(const bf16x4_t*)(Et + rm * 40 + kq * 8);
                *(bf16x4_t*)(Eplane + (size_t)rm * 4096 + (size_t)(nhalf + 16 * w + 4 * kq) * 2) = er;
            }

            if (h == 0) {
                peh0 = pe;
                __syncthreads();
            } else {
                // ---- 5. PV once per pair: A=[peh0|pe], B=V0|V1 rows 16w+4g+j ----
                bf16x8_t pa8 = __builtin_shufflevector(peh0, pe, 0, 1, 2, 3, 4, 5, 6, 7);
                #pragma unroll
                for (int t = 0; t < 4; ++t) {
                    bf16x8_t vbf;
                    #pragma unroll
                    for (int j = 0; j < 4; ++j) {
                        const int rr = 16 * w + 4 * g + j;
                        vbf[j]     = *(const __bf16*)(lds + V0B + rr * KSTR + (16 * t + c) * 2);
                        vbf[4 + j] = *(const __bf16*)(lds + V1B + rr * KSTR + (16 * t + c) * 2);
                    }
                    of[t] = __builtin_amdgcn_mfma_f32_16x16x32_bf16(pa8, vbf, of[t], 0, 0, 0);
                }
                __syncthreads();
            }
        }
    }

    // =============== epilogue ===============
    {
        float* Ow = (float*)(lds + w * 4096);
        #pragma unroll
        for (int t = 0; t < 4; ++t)
            #pragma unroll
            for (int r = 0; r < 4; ++r)
                Ow[(g * 4 + r) * 64 + t * 16 + c] = of[t][r];
    }
    lsum += __shfl_xor(lsum, 16);
    lsum += __shfl_xor(lsum, 32);
    float* Lbuf = (float*)(lds + LBB);
    if (l < 16) Lbuf[w * 16 + l] = lsum;
    __syncthreads();

    if (tid < 16) {
        float s = 0.f;
        #pragma unroll
        for (int ww = 0; ww < 8; ++ww) s += Lbuf[ww * 16 + tid];
        sums[(size_t)bid * 16 + tid] = s;
    }

    if (tid < 256) {
        const int row = tid >> 4;
        const int dc  = (tid & 15) * 4;
        f32x4_t o = {0.f, 0.f, 0.f, 0.f};
        #pragma unroll
        for (int ww = 0; ww < 8; ++ww)
            o += *(const f32x4_t*)((const float*)(lds + ww * 4096) + row * 64 + dc);
        *(f32x4_t*)(out0 + ((size_t)(b * N_ + m0 + row)) * D_ + dc) = o;   // unnormalized
    }
}

// ============ K3: out1 = E * rinv (fp32, streaming), out0 *= rinv in place ============
__global__ __launch_bounds__(512, 4)
void attn_k3(const float* __restrict__ sums,
             float* __restrict__ out0,
             float* __restrict__ out1)
{
    const int tid = threadIdx.x;
    const int bid = (int)blockIdx.x;
    const int b  = bid >> 7;
    const int m0 = (bid & 127) << 4;
    const size_t tb = ((size_t)(b * N_ + m0)) * N_;

    const int row = tid >> 5;
    const int ch  = tid & 31;
    const float ri = 1.0f / sums[(size_t)bid * 16 + row];

    const char* esrc = (const char*)out1 + tb * 4 + 65536 + (size_t)row * 4096 + ch * 128;
    bf16x8_t e[8];
    #pragma unroll
    for (int i = 0; i < 8; ++i) e[i] = *(const bf16x8_t*)(esrc + i * 16);
    __syncthreads();

    float* dst = out1 + tb + (size_t)row * N_ + ch * 64;
    #pragma unroll
    for (int i = 0; i < 8; ++i) {
        f32x4_t o0, o1;
        #pragma unroll
        for (int j = 0; j < 4; ++j) {
            o0[j] = (float)e[i][j]     * ri;
            o1[j] = (float)e[i][4 + j] * ri;
        }
        *(f32x4_t*)(dst + i * 8)     = o0;
        *(f32x4_t*)(dst + i * 8 + 4) = o1;
    }

    if (tid < 256) {
        const int r2 = tid >> 4;
        const int dc = (tid & 15) * 4;
        const float ri2 = 1.0f / sums[(size_t)bid * 16 + r2];
        float* p = out0 + ((size_t)(b * N_ + m0 + r2)) * D_ + dc;
        f32x4_t o = *(const f32x4_t*)p;
        o.x *= ri2; o.y *= ri2; o.z *= ri2; o.w *= ri2;
        *(f32x4_t*)p = o;
    }
}

extern "C" void kernel_launch(void* const* d_in, const int* in_sizes, int n_in,
                              void* d_out, int out_size, void* d_ws, size_t ws_size,
                              hipStream_t stream) {
    (void)in_sizes; (void)n_in; (void)out_size; (void)ws_size;
    const float* q = (const float*)d_in[0];
    const float* k = (const float*)d_in[1];
    const float* v = (const float*)d_in[2];
    const int* mask = (const int*)d_in[3];
    float* out0 = (float*)d_out;                          // [B,N,D]
    float* out1 = out0 + (size_t)B_ * N_ * D_;            // [B,N,N]
    float* sums = (float*)d_ws;                           // 2048*16 f32 = 128KB
    attn_k1<<<dim3(B_ * (N_ / 16)), dim3(512), 0, stream>>>(q, k, v, mask, out0, out1, sums);
    attn_k3<<<dim3(B_ * (N_ / 16)), dim3(512), 0, stream>>>(sums, out0, out1);
}

// Round 10
// 263.341 us; speedup vs baseline: 1.3492x; 1.2256x over previous
//
#include <hip/hip_runtime.h>
#include <hip/hip_bf16.h>
#include <cstdint>

#define B_ 16
#define N_ 2048
#define D_ 64

typedef __bf16 bf16x8_t __attribute__((ext_vector_type(8)));
typedef __bf16 bf16x4_t __attribute__((ext_vector_type(4)));
typedef float f32x4_t __attribute__((ext_vector_type(4)));
typedef int   int4_t  __attribute__((ext_vector_type(4)));

// LDS map. KSTR=144 -> every K/V row is 16B-aligned (b128-legal reads).
#define KSTR 144
#define KHI  0
#define KLO  18432
#define V0B  36864
#define V1B  55296
#define MB_  73728
#define MSTR 132
#define LBB  75840
#define RIB  76352
#define LDSZ 76416
#define ETB  V0B            // epilogue overlay (V0 dead)

// barrier WITHOUT vmcnt drain: prefetch global loads stay in flight.
// lgkmcnt(0) orders LDS writes; sched_barrier pins post-barrier DS ops (rule #18).
#define SBAR() do { asm volatile("s_waitcnt lgkmcnt(0)" ::: "memory");  \
                    __builtin_amdgcn_s_barrier();                        \
                    __builtin_amdgcn_sched_barrier(0); } while (0)

__device__ __forceinline__ void split8r(const f32x4_t a, const f32x4_t bq, bf16x8_t& h, bf16x8_t& lo) {
    #pragma unroll
    for (int j = 0; j < 4; ++j) {
        __bf16 h0 = (__bf16)a[j];
        h[j] = h0;     lo[j]     = (__bf16)(a[j]  - (float)h0);
        __bf16 h1 = (__bf16)bq[j];
        h[4 + j] = h1; lo[4 + j] = (__bf16)(bq[j] - (float)h1);
    }
}
__device__ __forceinline__ void split4r(const f32x4_t a, bf16x4_t& h, bf16x4_t& lo) {
    #pragma unroll
    for (int j = 0; j < 4; ++j) {
        __bf16 h0 = (__bf16)a[j];
        h[j] = h0;  lo[j] = (__bf16)(a[j] - (float)h0);
    }
}

__global__ __launch_bounds__(512, 4)
void attn_fused(const float* __restrict__ qg,
                const float* __restrict__ kg,
                const float* __restrict__ vg,
                const int*   __restrict__ mg,
                float* __restrict__ out0,
                float* __restrict__ out1)
{
    __shared__ __align__(16) char lds[LDSZ];

    const int tid = threadIdx.x;
    const int w = tid >> 6, l = tid & 63, g = l >> 4, c = l & 15;

    // XCD-chunked bijective swizzle (2048 % 8 == 0)
    const int bid = ((int)blockIdx.x & 7) * 256 + ((int)blockIdx.x >> 3);
    const int b  = bid >> 7;
    const int m0 = (bid & 127) << 4;

    bf16x8_t qh0, ql0, qh1, ql1;
    {
        const float* qrow = qg + ((size_t)(b * N_ + m0 + c)) * D_ + g * 8;
        split8r(*(const f32x4_t*)qrow, *(const f32x4_t*)(qrow + 4), qh0, ql0);
        split8r(*(const f32x4_t*)(qrow + 32), *(const f32x4_t*)(qrow + 36), qh1, ql1);
    }

    const int krow_ = tid >> 4;            // staging row, +32*u
    const int kcol_ = (tid & 15) * 4;      // float col
    const int mrow_ = tid >> 5;
    const int mcol_ = (tid & 31) * 4;
    const int* mgrow = mg + (size_t)(b * N_ + m0 + mrow_) * N_ + mcol_;

    float lsum = 0.f;
    f32x4_t of[4] = {};        // lane(g,c): O_unnorm[m=4g+r][d=16t+c]
    bf16x4_t paE[16];          // per half: P~[m0+c][h*128+16w+4g+r] (statically indexed)

    f32x4_t kin[4], vin[4]; int4_t min_;
    #pragma unroll
    for (int u = 0; u < 4; ++u) {
        const size_t roff = ((size_t)(b * N_ + krow_ + 32 * u)) * D_ + kcol_;
        kin[u] = *(const f32x4_t*)(kg + roff);
        vin[u] = *(const f32x4_t*)(vg + roff);
    }
    min_ = *(const int4_t*)(mgrow);

    #pragma unroll
    for (int p = 0; p < 8; ++p) {
        #pragma unroll
        for (int h = 0; h < 2; ++h) {
            const int nhalf = p * 256 + h * 128;
            const int vbase = h ? V1B : V0B;

            // ---- 1. stage current half from prefetched regs (b64 LDS writes) ----
            #pragma unroll
            for (int u = 0; u < 4; ++u) {
                const int row = krow_ + 32 * u;
                bf16x4_t kh, klo;
                split4r(kin[u], kh, klo);
                *(bf16x4_t*)(lds + KHI + row * KSTR + kcol_ * 2) = kh;
                *(bf16x4_t*)(lds + KLO + row * KSTR + kcol_ * 2) = klo;
                bf16x4_t v4;
                #pragma unroll
                for (int j = 0; j < 4; ++j) v4[j] = (__bf16)vin[u][j];
                *(bf16x4_t*)(lds + vbase + row * KSTR + kcol_ * 2) = v4;
            }
            {
                unsigned mbytes = 0;
                #pragma unroll
                for (int j = 0; j < 4; ++j) mbytes |= (min_[j] ? 1u : 0u) << (8 * j);
                *(unsigned*)(lds + MB_ + mrow_ * MSTR + mcol_) = mbytes;
            }
            SBAR();                                     // no vmcnt drain!

            // ---- 2. issue next-half loads (stay in flight across compute+barriers) ----
            if ((p < 7) || (h < 1)) {
                const int nnext = nhalf + 128;
                #pragma unroll
                for (int u = 0; u < 4; ++u) {
                    const size_t roff = ((size_t)(b * N_ + nnext + krow_ + 32 * u)) * D_ + kcol_;
                    kin[u] = *(const f32x4_t*)(kg + roff);
                    vin[u] = *(const f32x4_t*)(vg + roff);
                }
                min_ = *(const int4_t*)(mgrow + nnext);
            }

            // ---- 3. QK^T (swapped): b128 frag reads, 6 MFMA, mask+exp ----
            bf16x4_t pe;
            {
                const char* ka = lds + KHI + (16 * w + c) * KSTR + g * 16;
                const char* la = lds + KLO + (16 * w + c) * KSTR + g * 16;
                bf16x8_t ka0 = *(const bf16x8_t*)(ka);
                bf16x8_t ka1 = *(const bf16x8_t*)(ka + 64);
                bf16x8_t la0 = *(const bf16x8_t*)(la);
                bf16x8_t la1 = *(const bf16x8_t*)(la + 64);
                f32x4_t acc = {0.f, 0.f, 0.f, 0.f};
                __builtin_amdgcn_s_setprio(1);
                acc = __builtin_amdgcn_mfma_f32_16x16x32_bf16(ka0, qh0, acc, 0, 0, 0);
                acc = __builtin_amdgcn_mfma_f32_16x16x32_bf16(ka1, qh1, acc, 0, 0, 0);
                acc = __builtin_amdgcn_mfma_f32_16x16x32_bf16(la0, qh0, acc, 0, 0, 0);
                acc = __builtin_amdgcn_mfma_f32_16x16x32_bf16(la1, qh1, acc, 0, 0, 0);
                acc = __builtin_amdgcn_mfma_f32_16x16x32_bf16(ka0, ql0, acc, 0, 0, 0);
                acc = __builtin_amdgcn_mfma_f32_16x16x32_bf16(ka1, ql1, acc, 0, 0, 0);
                __builtin_amdgcn_s_setprio(0);
                const unsigned mu = *(const unsigned*)(lds + MB_ + c * MSTR + 16 * w + 4 * g);
                #pragma unroll
                for (int r = 0; r < 4; ++r) {
                    float e = ((mu >> (8 * r)) & 255u) ? 0.f : __expf(acc[r]);
                    lsum += e;
                    pe[r] = (__bf16)e;
                }
            }
            paE[2 * p + h] = pe;

            if (h == 0) {
                SBAR();                                 // K/M tiles reusable
            } else {
                // ---- 4. PV once per pair ----
                bf16x8_t pa8 = __builtin_shufflevector(paE[2 * p], paE[2 * p + 1],
                                                       0, 1, 2, 3, 4, 5, 6, 7);
                __builtin_amdgcn_s_setprio(1);
                #pragma unroll
                for (int t = 0; t < 4; ++t) {
                    bf16x8_t vbf;
                    #pragma unroll
                    for (int j = 0; j < 4; ++j) {
                        const int rr = 16 * w + 4 * g + j;
                        vbf[j]     = *(const __bf16*)(lds + V0B + rr * KSTR + (16 * t + c) * 2);
                        vbf[4 + j] = *(const __bf16*)(lds + V1B + rr * KSTR + (16 * t + c) * 2);
                    }
                    of[t] = __builtin_amdgcn_mfma_f32_16x16x32_bf16(pa8, vbf, of[t], 0, 0, 0);
                }
                __builtin_amdgcn_s_setprio(0);
                SBAR();                                 // V0/V1/K/M reusable
            }
        }
    }

    // =============== epilogue (R7-verified) ===============
    {
        float* Ow = (float*)(lds + w * 4096);           // dead KHI/KLO region
        #pragma unroll
        for (int t = 0; t < 4; ++t)
            #pragma unroll
            for (int r = 0; r < 4; ++r)
                Ow[(g * 4 + r) * 64 + t * 16 + c] = of[t][r];
    }
    lsum += __shfl_xor(lsum, 16);
    lsum += __shfl_xor(lsum, 32);
    float* Lbuf = (float*)(lds + LBB);
    if (l < 16) Lbuf[w * 16 + l] = lsum;
    __syncthreads();

    float* Rinv = (float*)(lds + RIB);
    if (tid < 16) {
        float s = 0.f;
        #pragma unroll
        for (int ww = 0; ww < 8; ++ww) s += Lbuf[ww * 16 + tid];
        Rinv[tid] = 1.0f / s;
    }
    __syncthreads();

    if (tid < 256) {
        const int row = tid >> 4;
        const int dc  = (tid & 15) * 4;
        const float ri = Rinv[row];
        f32x4_t o = {0.f, 0.f, 0.f, 0.f};
        #pragma unroll
        for (int ww = 0; ww < 8; ++ww)
            o += *(const f32x4_t*)((const float*)(lds + ww * 4096) + row * 64 + dc);
        o.x *= ri; o.y *= ri; o.z *= ri; o.w *= ri;
        *(f32x4_t*)(out0 + ((size_t)(b * N_ + m0 + row)) * D_ + dc) = o;
    }

    // out1: per-wave transpose bounce (Et overlays dead V0), coalesced f32x4 stores
    {
        char* Et = lds + ETB + w * 640;                 // [16][20] bf16
        const int   rm  = l >> 2;
        const int   kq  = l & 3;
        const float riR = Rinv[rm];
        float* o1row = out1 + (size_t)(b * N_ + m0 + rm) * N_;
        #pragma unroll
        for (int u = 0; u < 16; ++u) {
            const int n0 = u * 128 + 16 * w;
            *(bf16x4_t*)(Et + c * 40 + g * 8) = paE[u];     // E[m=c][local 4g+r]
            bf16x4_t er = *(const bf16x4_t*)(Et + rm * 40 + kq * 8);
            f32x4_t o4;
            #pragma unroll
            for (int j = 0; j < 4; ++j) o4[j] = (float)er[j] * riR;
            *(f32x4_t*)(o1row + n0 + kq * 4) = o4;
        }
    }
}

extern "C" void kernel_launch(void* const* d_in, const int* in_sizes, int n_in,
                              void* d_out, int out_size, void* d_ws, size_t ws_size,
                              hipStream_t stream) {
    (void)in_sizes; (void)n_in; (void)out_size; (void)d_ws; (void)ws_size;
    const float* q = (const float*)d_in[0];
    const float* k = (const float*)d_in[1];
    const float* v = (const float*)d_in[2];
    const int* mask = (const int*)d_in[3];
    float* out0 = (float*)d_out;                          // [B,N,D]
    float* out1 = out0 + (size_t)B_ * N_ * D_;            // [B,N,N]
    attn_fused<<<dim3(B_ * (N_ / 16)), dim3(512), 0, stream>>>(q, k, v, mask, out0, out1);
}

// Round 11
// 192.861 us; speedup vs baseline: 1.8423x; 1.3654x over previous
//
#include <hip/hip_runtime.h>
#include <hip/hip_bf16.h>
#include <cstdint>

#define B_ 16
#define N_ 2048
#define D_ 64

typedef __bf16 bf16x8_t __attribute__((ext_vector_type(8)));
typedef __bf16 bf16x4_t __attribute__((ext_vector_type(4)));
typedef float f32x4_t __attribute__((ext_vector_type(4)));
typedef int   int4_t  __attribute__((ext_vector_type(4)));

// LDS map. KSTR=144 -> K/V rows 16B-aligned (b128-legal).
#define KSTR 144
#define KHI  0
#define KLO  18432
#define V0B  36864
#define V1B  55296
#define MB_  73728          // [32 m][132 B] mask bytes
#define MSTR 132
#define LBB  77952          // 8 waves x 32 row-sums f32
#define RIB  78976          // 32 x rinv
#define LDSZ 79104
#define ETB  V0B            // epilogue overlay (V0 dead)

// barrier WITHOUT vmcnt drain (prefetch stays in flight); rule #18 fence.
#define SBAR() do { asm volatile("s_waitcnt lgkmcnt(0)" ::: "memory");  \
                    __builtin_amdgcn_s_barrier();                        \
                    __builtin_amdgcn_sched_barrier(0); } while (0)

__device__ __forceinline__ void split8r(const f32x4_t a, const f32x4_t bq, bf16x8_t& h, bf16x8_t& lo) {
    #pragma unroll
    for (int j = 0; j < 4; ++j) {
        __bf16 h0 = (__bf16)a[j];
        h[j] = h0;     lo[j]     = (__bf16)(a[j]  - (float)h0);
        __bf16 h1 = (__bf16)bq[j];
        h[4 + j] = h1; lo[4 + j] = (__bf16)(bq[j] - (float)h1);
    }
}
__device__ __forceinline__ void split4r(const f32x4_t a, bf16x4_t& h, bf16x4_t& lo) {
    #pragma unroll
    for (int j = 0; j < 4; ++j) {
        __bf16 h0 = (__bf16)a[j];
        h[j] = h0;  lo[j] = (__bf16)(a[j] - (float)h0);
    }
}

__global__ __launch_bounds__(512, 2)
void attn_fused(const float* __restrict__ qg,
                const float* __restrict__ kg,
                const float* __restrict__ vg,
                const int*   __restrict__ mg,
                float* __restrict__ out0,
                float* __restrict__ out1)
{
    __shared__ __align__(16) char lds[LDSZ];

    const int tid = threadIdx.x;
    const int w = tid >> 6, l = tid & 63, g = l >> 4, c = l & 15;

    // 1024 blocks; XCD-chunked bijective swizzle (1024 % 8 == 0)
    const int bid = ((int)blockIdx.x & 7) * 128 + ((int)blockIdx.x >> 3);
    const int b  = bid >> 6;
    const int m0 = (bid & 63) << 5;          // 32-row m-tile

    // Q fragments for BOTH 16-row q-tiles
    bf16x8_t q0h0, q0l0, q0h1, q0l1, q1h0, q1l0, q1h1, q1l1;
    {
        const float* qr0 = qg + ((size_t)(b * N_ + m0 + c)) * D_ + g * 8;
        split8r(*(const f32x4_t*)qr0, *(const f32x4_t*)(qr0 + 4), q0h0, q0l0);
        split8r(*(const f32x4_t*)(qr0 + 32), *(const f32x4_t*)(qr0 + 36), q0h1, q0l1);
        const float* qr1 = qr0 + 16 * D_;
        split8r(*(const f32x4_t*)qr1, *(const f32x4_t*)(qr1 + 4), q1h0, q1l0);
        split8r(*(const f32x4_t*)(qr1 + 32), *(const f32x4_t*)(qr1 + 36), q1h1, q1l1);
    }

    const int krow_ = tid >> 4;              // staging row, +32*u
    const int kcol_ = (tid & 15) * 4;        // float col
    const int mrow_ = tid >> 4;              // mask row 0..31
    const int mcol8 = (tid & 15) * 8;        // 8 int cols per thread
    const int* mgrow = mg + (size_t)(b * N_ + m0 + mrow_) * N_ + mcol8;

    float lsum0 = 0.f, lsum1 = 0.f;
    f32x4_t of0[4] = {}, of1[4] = {};
    bf16x4_t paE0[16], paE1[16];             // statically indexed (full unroll)

    f32x4_t kin[4], vin[4]; int4_t mA, mB;
    #pragma unroll
    for (int u = 0; u < 4; ++u) {
        const size_t roff = ((size_t)(b * N_ + krow_ + 32 * u)) * D_ + kcol_;
        kin[u] = *(const f32x4_t*)(kg + roff);
        vin[u] = *(const f32x4_t*)(vg + roff);
    }
    mA = *(const int4_t*)(mgrow);
    mB = *(const int4_t*)(mgrow + 4);

    #pragma unroll
    for (int p = 0; p < 8; ++p) {
        #pragma unroll
        for (int h = 0; h < 2; ++h) {
            const int nhalf = p * 256 + h * 128;
            const int vbase = h ? V1B : V0B;

            // ---- 1. stage current half from prefetched regs ----
            #pragma unroll
            for (int u = 0; u < 4; ++u) {
                const int row = krow_ + 32 * u;
                bf16x4_t kh, klo;
                split4r(kin[u], kh, klo);
                *(bf16x4_t*)(lds + KHI + row * KSTR + kcol_ * 2) = kh;
                *(bf16x4_t*)(lds + KLO + row * KSTR + kcol_ * 2) = klo;
                bf16x4_t v4;
                #pragma unroll
                for (int j = 0; j < 4; ++j) v4[j] = (__bf16)vin[u][j];
                *(bf16x4_t*)(lds + vbase + row * KSTR + kcol_ * 2) = v4;
            }
            {
                unsigned mb0 = 0, mb1 = 0;
                #pragma unroll
                for (int j = 0; j < 4; ++j) {
                    mb0 |= (mA[j] ? 1u : 0u) << (8 * j);
                    mb1 |= (mB[j] ? 1u : 0u) << (8 * j);
                }
                *(unsigned*)(lds + MB_ + mrow_ * MSTR + mcol8)     = mb0;
                *(unsigned*)(lds + MB_ + mrow_ * MSTR + mcol8 + 4) = mb1;
            }
            SBAR();

            // ---- 2. issue next-half loads (in flight across compute) ----
            if ((p < 7) || (h < 1)) {
                const int nnext = nhalf + 128;
                #pragma unroll
                for (int u = 0; u < 4; ++u) {
                    const size_t roff = ((size_t)(b * N_ + nnext + krow_ + 32 * u)) * D_ + kcol_;
                    kin[u] = *(const f32x4_t*)(kg + roff);
                    vin[u] = *(const f32x4_t*)(vg + roff);
                }
                mA = *(const int4_t*)(mgrow + nnext);
                mB = *(const int4_t*)(mgrow + nnext + 4);
            }

            // ---- 3. QK^T (swapped) for both q-tiles: shared K frags, 12 MFMA ----
            bf16x4_t pe0, pe1;
            {
                const char* ka = lds + KHI + (16 * w + c) * KSTR + g * 16;
                const char* la = lds + KLO + (16 * w + c) * KSTR + g * 16;
                bf16x8_t ka0 = *(const bf16x8_t*)(ka);
                bf16x8_t ka1 = *(const bf16x8_t*)(ka + 64);
                bf16x8_t la0 = *(const bf16x8_t*)(la);
                bf16x8_t la1 = *(const bf16x8_t*)(la + 64);
                f32x4_t a0 = {0.f, 0.f, 0.f, 0.f};
                f32x4_t a1 = {0.f, 0.f, 0.f, 0.f};
                __builtin_amdgcn_s_setprio(1);
                a0 = __builtin_amdgcn_mfma_f32_16x16x32_bf16(ka0, q0h0, a0, 0, 0, 0);
                a1 = __builtin_amdgcn_mfma_f32_16x16x32_bf16(ka0, q1h0, a1, 0, 0, 0);
                a0 = __builtin_amdgcn_mfma_f32_16x16x32_bf16(ka1, q0h1, a0, 0, 0, 0);
                a1 = __builtin_amdgcn_mfma_f32_16x16x32_bf16(ka1, q1h1, a1, 0, 0, 0);
                a0 = __builtin_amdgcn_mfma_f32_16x16x32_bf16(la0, q0h0, a0, 0, 0, 0);
                a1 = __builtin_amdgcn_mfma_f32_16x16x32_bf16(la0, q1h0, a1, 0, 0, 0);
                a0 = __builtin_amdgcn_mfma_f32_16x16x32_bf16(la1, q0h1, a0, 0, 0, 0);
                a1 = __builtin_amdgcn_mfma_f32_16x16x32_bf16(la1, q1h1, a1, 0, 0, 0);
                a0 = __builtin_amdgcn_mfma_f32_16x16x32_bf16(ka0, q0l0, a0, 0, 0, 0);
                a1 = __builtin_amdgcn_mfma_f32_16x16x32_bf16(ka0, q1l0, a1, 0, 0, 0);
                a0 = __builtin_amdgcn_mfma_f32_16x16x32_bf16(ka1, q0l1, a0, 0, 0, 0);
                a1 = __builtin_amdgcn_mfma_f32_16x16x32_bf16(ka1, q1l1, a1, 0, 0, 0);
                __builtin_amdgcn_s_setprio(0);
                const unsigned mu0 = *(const unsigned*)(lds + MB_ + c * MSTR + 16 * w + 4 * g);
                const unsigned mu1 = *(const unsigned*)(lds + MB_ + (16 + c) * MSTR + 16 * w + 4 * g);
                #pragma unroll
                for (int r = 0; r < 4; ++r) {
                    float e0 = ((mu0 >> (8 * r)) & 255u) ? 0.f : __expf(a0[r]);
                    float e1 = ((mu1 >> (8 * r)) & 255u) ? 0.f : __expf(a1[r]);
                    lsum0 += e0; lsum1 += e1;
                    pe0[r] = (__bf16)e0; pe1[r] = (__bf16)e1;
                }
            }
            paE0[2 * p + h] = pe0;
            paE1[2 * p + h] = pe1;

            if (h == 0) {
                SBAR();
            } else {
                // ---- 4. PV for both q-tiles: shared V reads, 8 MFMA ----
                bf16x8_t pa80 = __builtin_shufflevector(paE0[2 * p], paE0[2 * p + 1],
                                                        0, 1, 2, 3, 4, 5, 6, 7);
                bf16x8_t pa81 = __builtin_shufflevector(paE1[2 * p], paE1[2 * p + 1],
                                                        0, 1, 2, 3, 4, 5, 6, 7);
                __builtin_amdgcn_s_setprio(1);
                #pragma unroll
                for (int t = 0; t < 4; ++t) {
                    bf16x8_t vbf;
                    #pragma unroll
                    for (int j = 0; j < 4; ++j) {
                        const int rr = 16 * w + 4 * g + j;
                        vbf[j]     = *(const __bf16*)(lds + V0B + rr * KSTR + (16 * t + c) * 2);
                        vbf[4 + j] = *(const __bf16*)(lds + V1B + rr * KSTR + (16 * t + c) * 2);
                    }
                    of0[t] = __builtin_amdgcn_mfma_f32_16x16x32_bf16(pa80, vbf, of0[t], 0, 0, 0);
                    of1[t] = __builtin_amdgcn_mfma_f32_16x16x32_bf16(pa81, vbf, of1[t], 0, 0, 0);
                }
                __builtin_amdgcn_s_setprio(0);
                SBAR();
            }
        }
    }

    // =============== epilogue ===============
    // row sums (both tiles) -> Lbuf -> Rinv[32]
    lsum0 += __shfl_xor(lsum0, 16); lsum0 += __shfl_xor(lsum0, 32);
    lsum1 += __shfl_xor(lsum1, 16); lsum1 += __shfl_xor(lsum1, 32);
    float* Lbuf = (float*)(lds + LBB);
    if (l < 16) {
        Lbuf[w * 32 + l]      = lsum0;
        Lbuf[w * 32 + 16 + l] = lsum1;
    }

    // O partials, m-tile 0, into dead K region
    {
        float* Ow = (float*)(lds + w * 4096);
        #pragma unroll
        for (int t = 0; t < 4; ++t)
            #pragma unroll
            for (int r = 0; r < 4; ++r)
                Ow[(g * 4 + r) * 64 + t * 16 + c] = of0[t][r];
    }
    __syncthreads();

    float* Rinv = (float*)(lds + RIB);
    if (tid < 32) {
        float s = 0.f;
        #pragma unroll
        for (int ww = 0; ww < 8; ++ww) s += Lbuf[ww * 32 + tid];
        Rinv[tid] = 1.0f / s;
    }
    __syncthreads();

    if (tid < 256) {
        const int row = tid >> 4;
        const int dc  = (tid & 15) * 4;
        const float ri = Rinv[row];
        f32x4_t o = {0.f, 0.f, 0.f, 0.f};
        #pragma unroll
        for (int ww = 0; ww < 8; ++ww)
            o += *(const f32x4_t*)((const float*)(lds + ww * 4096) + row * 64 + dc);
        o.x *= ri; o.y *= ri; o.z *= ri; o.w *= ri;
        *(f32x4_t*)(out0 + ((size_t)(b * N_ + m0 + row)) * D_ + dc) = o;
    }
    __syncthreads();

    // O partials, m-tile 1 (reuse region)
    {
        float* Ow = (float*)(lds + w * 4096);
        #pragma unroll
        for (int t = 0; t < 4; ++t)
            #pragma unroll
            for (int r = 0; r < 4; ++r)
                Ow[(g * 4 + r) * 64 + t * 16 + c] = of1[t][r];
    }
    __syncthreads();

    if (tid < 256) {
        const int row = tid >> 4;
        const int dc  = (tid & 15) * 4;
        const float ri = Rinv[16 + row];
        f32x4_t o = {0.f, 0.f, 0.f, 0.f};
        #pragma unroll
        for (int ww = 0; ww < 8; ++ww)
            o += *(const f32x4_t*)((const float*)(lds + ww * 4096) + row * 64 + dc);
        o.x *= ri; o.y *= ri; o.z *= ri; o.w *= ri;
        *(f32x4_t*)(out0 + ((size_t)(b * N_ + m0 + 16 + row)) * D_ + dc) = o;
    }

    // out1: per-wave transpose bounce (Et overlays dead V0), both m-tiles
    {
        char* Et = lds + ETB + w * 640;                 // [16][20] bf16, wave-private
        const int   rm  = l >> 2;
        const int   kq  = l & 3;
        const float ri0 = Rinv[rm];
        const float ri1 = Rinv[16 + rm];
        float* o1r0 = out1 + (size_t)(b * N_ + m0 + rm) * N_;
        float* o1r1 = out1 + (size_t)(b * N_ + m0 + 16 + rm) * N_;
        #pragma unroll
        for (int u = 0; u < 16; ++u) {
            const int n0 = u * 128 + 16 * w;
            *(bf16x4_t*)(Et + c * 40 + g * 8) = paE0[u];
            bf16x4_t er0 = *(const bf16x4_t*)(Et + rm * 40 + kq * 8);
            f32x4_t o40;
            #pragma unroll
            for (int j = 0; j < 4; ++j) o40[j] = (float)er0[j] * ri0;
            *(f32x4_t*)(o1r0 + n0 + kq * 4) = o40;

            *(bf16x4_t*)(Et + c * 40 + g * 8) = paE1[u];
            bf16x4_t er1 = *(const bf16x4_t*)(Et + rm * 40 + kq * 8);
            f32x4_t o41;
            #pragma unroll
            for (int j = 0; j < 4; ++j) o41[j] = (float)er1[j] * ri1;
            *(f32x4_t*)(o1r1 + n0 + kq * 4) = o41;
        }
    }
}

extern "C" void kernel_launch(void* const* d_in, const int* in_sizes, int n_in,
                              void* d_out, int out_size, void* d_ws, size_t ws_size,
                              hipStream_t stream) {
    (void)in_sizes; (void)n_in; (void)out_size; (void)d_ws; (void)ws_size;
    const float* q = (const float*)d_in[0];
    const float* k = (const float*)d_in[1];
    const float* v = (const float*)d_in[2];
    const int* mask = (const int*)d_in[3];
    float* out0 = (float*)d_out;                          // [B,N,D]
    float* out1 = out0 + (size_t)B_ * N_ * D_;            // [B,N,N]
    attn_fused<<<dim3(B_ * (N_ / 32)), dim3(512), 0, stream>>>(q, k, v, mask, out0, out1);
}

// Round 12
// 175.325 us; speedup vs baseline: 2.0266x; 1.1000x over previous
//
#include <hip/hip_runtime.h>
#include <hip/hip_bf16.h>
#include <cstdint>

#define B_ 16
#define N_ 2048
#define D_ 64

typedef __bf16 bf16x8_t __attribute__((ext_vector_type(8)));
typedef __bf16 bf16x4_t __attribute__((ext_vector_type(4)));
typedef float f32x4_t __attribute__((ext_vector_type(4)));
typedef int   int4_t  __attribute__((ext_vector_type(4)));

// LDS map (157KB of 160KB; 1 block/CU — already reg-bound there).
// K double-buffered: buf b at b*36864 (hi +0, lo +18432), rows [128][KSTR=144B]
// V 4 slots:        slot s at 73728 + s*18432
// M double-buffered: buf b at 147456 + b*4224, [32 m][132 B]
// Lbuf 155904 (8w x 32 f32), Rinv 156928 (32 f32)
#define KSTR 144
#define VBASE 73728
#define MBASE 147456
#define MSTR 132
#define LBB  155904
#define RIB  156928
#define LDSZ 157056

// barrier WITHOUT vmcnt drain; rule #18 fence after.
#define SBAR() do { asm volatile("s_waitcnt lgkmcnt(0)" ::: "memory");  \
                    __builtin_amdgcn_s_barrier();                        \
                    __builtin_amdgcn_sched_barrier(0); } while (0)

__device__ __forceinline__ void split8r(const f32x4_t a, const f32x4_t bq, bf16x8_t& h, bf16x8_t& lo) {
    #pragma unroll
    for (int j = 0; j < 4; ++j) {
        __bf16 h0 = (__bf16)a[j];
        h[j] = h0;     lo[j]     = (__bf16)(a[j]  - (float)h0);
        __bf16 h1 = (__bf16)bq[j];
        h[4 + j] = h1; lo[4 + j] = (__bf16)(bq[j] - (float)h1);
    }
}
__device__ __forceinline__ void split4r(const f32x4_t a, bf16x4_t& h, bf16x4_t& lo) {
    #pragma unroll
    for (int j = 0; j < 4; ++j) {
        __bf16 h0 = (__bf16)a[j];
        h[j] = h0;  lo[j] = (__bf16)(a[j] - (float)h0);
    }
}

__global__ __launch_bounds__(512, 2)
void attn_fused(const float* __restrict__ qg,
                const float* __restrict__ kg,
                const float* __restrict__ vg,
                const int*   __restrict__ mg,
                float* __restrict__ out0,
                float* __restrict__ out1)
{
    __shared__ __align__(16) char lds[LDSZ];

    const int tid = threadIdx.x;
    const int w = tid >> 6, l = tid & 63, g = l >> 4, c = l & 15;

    // 1024 blocks; XCD-chunked bijective swizzle (1024 % 8 == 0)
    const int bid = ((int)blockIdx.x & 7) * 128 + ((int)blockIdx.x >> 3);
    const int b  = bid >> 6;
    const int m0 = (bid & 63) << 5;          // 32-row m-tile

    // Q fragments for both 16-row q-tiles
    bf16x8_t q0h0, q0l0, q0h1, q0l1, q1h0, q1l0, q1h1, q1l1;
    {
        const float* qr0 = qg + ((size_t)(b * N_ + m0 + c)) * D_ + g * 8;
        split8r(*(const f32x4_t*)qr0, *(const f32x4_t*)(qr0 + 4), q0h0, q0l0);
        split8r(*(const f32x4_t*)(qr0 + 32), *(const f32x4_t*)(qr0 + 36), q0h1, q0l1);
        const float* qr1 = qr0 + 16 * D_;
        split8r(*(const f32x4_t*)qr1, *(const f32x4_t*)(qr1 + 4), q1h0, q1l0);
        split8r(*(const f32x4_t*)(qr1 + 32), *(const f32x4_t*)(qr1 + 36), q1h1, q1l1);
    }

    const int krow_ = tid >> 4;              // staging row, +32*u
    const int kcol_ = (tid & 15) * 4;        // float col
    const int mrow_ = tid >> 4;              // mask row 0..31
    const int mcol8 = (tid & 15) * 8;        // 8 int cols / thread
    const int* mgrow = mg + (size_t)(b * N_ + m0 + mrow_) * N_ + mcol8;

    float lsum0 = 0.f, lsum1 = 0.f;
    f32x4_t of0[4] = {}, of1[4] = {};
    bf16x4_t paE0[16], paE1[16];             // statically indexed (full unroll)

    f32x4_t kin[4], vin[4]; int4_t mA, mB;
    #pragma unroll
    for (int u = 0; u < 4; ++u) {
        const size_t roff = ((size_t)(b * N_ + krow_ + 32 * u)) * D_ + kcol_;
        kin[u] = *(const f32x4_t*)(kg + roff);
        vin[u] = *(const f32x4_t*)(vg + roff);
    }
    mA = *(const int4_t*)(mgrow);
    mB = *(const int4_t*)(mgrow + 4);

    #pragma unroll
    for (int i = 0; i < 16; ++i) {
        const int buf = i & 1;
        const int vs  = i & 3;
        char* KH = lds + buf * 36864;
        char* KL = KH + 18432;
        char* VS = lds + VBASE + vs * 18432;
        char* MT = lds + MBASE + buf * 4224;

        // ---- 1. stage half i from prefetched regs ----
        #pragma unroll
        for (int u = 0; u < 4; ++u) {
            const int row = krow_ + 32 * u;
            bf16x4_t kh, klo;
            split4r(kin[u], kh, klo);
            *(bf16x4_t*)(KH + row * KSTR + kcol_ * 2) = kh;
            *(bf16x4_t*)(KL + row * KSTR + kcol_ * 2) = klo;
            bf16x4_t v4;
            #pragma unroll
            for (int j = 0; j < 4; ++j) v4[j] = (__bf16)vin[u][j];
            *(bf16x4_t*)(VS + row * KSTR + kcol_ * 2) = v4;
        }
        {
            unsigned mb0 = 0, mb1 = 0;
            #pragma unroll
            for (int j = 0; j < 4; ++j) {
                mb0 |= (mA[j] ? 1u : 0u) << (8 * j);
                mb1 |= (mB[j] ? 1u : 0u) << (8 * j);
            }
            *(unsigned*)(MT + mrow_ * MSTR + mcol8)     = mb0;
            *(unsigned*)(MT + mrow_ * MSTR + mcol8 + 4) = mb1;
        }

        // ---- 2. issue loads for half i+1 (in flight across barrier + compute) ----
        if (i < 15) {
            const int nnext = (i + 1) * 128;
            #pragma unroll
            for (int u = 0; u < 4; ++u) {
                const size_t roff = ((size_t)(b * N_ + nnext + krow_ + 32 * u)) * D_ + kcol_;
                kin[u] = *(const f32x4_t*)(kg + roff);
                vin[u] = *(const f32x4_t*)(vg + roff);
            }
            mA = *(const int4_t*)(mgrow + nnext);
            mB = *(const int4_t*)(mgrow + nnext + 4);
        }
        SBAR();                               // the ONLY barrier this half

        // ---- 3. deferred PV for pair (i-2)/2 (V slots (i-2)&3, (i-1)&3) ----
        if ((i >= 2) && ((i & 1) == 0)) {
            const int pp = (i - 2) / 2;
            const char* VA = lds + VBASE + ((i - 2) & 3) * 18432;
            const char* VBs = lds + VBASE + ((i - 1) & 3) * 18432;
            bf16x8_t pa80 = __builtin_shufflevector(paE0[2 * pp], paE0[2 * pp + 1],
                                                    0, 1, 2, 3, 4, 5, 6, 7);
            bf16x8_t pa81 = __builtin_shufflevector(paE1[2 * pp], paE1[2 * pp + 1],
                                                    0, 1, 2, 3, 4, 5, 6, 7);
            __builtin_amdgcn_s_setprio(1);
            #pragma unroll
            for (int t = 0; t < 4; ++t) {
                bf16x8_t vbf;
                #pragma unroll
                for (int j = 0; j < 4; ++j) {
                    const int rr = 16 * w + 4 * g + j;
                    vbf[j]     = *(const __bf16*)(VA  + rr * KSTR + (16 * t + c) * 2);
                    vbf[4 + j] = *(const __bf16*)(VBs + rr * KSTR + (16 * t + c) * 2);
                }
                of0[t] = __builtin_amdgcn_mfma_f32_16x16x32_bf16(pa80, vbf, of0[t], 0, 0, 0);
                of1[t] = __builtin_amdgcn_mfma_f32_16x16x32_bf16(pa81, vbf, of1[t], 0, 0, 0);
            }
            __builtin_amdgcn_s_setprio(0);
        }

        // ---- 4. QK^T (swapped), 4 independent accumulator chains ----
        {
            const char* ka = KH + (16 * w + c) * KSTR + g * 16;
            const char* la = KL + (16 * w + c) * KSTR + g * 16;
            bf16x8_t ka0 = *(const bf16x8_t*)(ka);
            bf16x8_t ka1 = *(const bf16x8_t*)(ka + 64);
            bf16x8_t la0 = *(const bf16x8_t*)(la);
            bf16x8_t la1 = *(const bf16x8_t*)(la + 64);
            f32x4_t z = {0.f, 0.f, 0.f, 0.f};
            __builtin_amdgcn_s_setprio(1);
            f32x4_t a0a = __builtin_amdgcn_mfma_f32_16x16x32_bf16(ka0, q0h0, z, 0, 0, 0);
            f32x4_t a0b = __builtin_amdgcn_mfma_f32_16x16x32_bf16(ka1, q0h1, z, 0, 0, 0);
            f32x4_t a1a = __builtin_amdgcn_mfma_f32_16x16x32_bf16(ka0, q1h0, z, 0, 0, 0);
            f32x4_t a1b = __builtin_amdgcn_mfma_f32_16x16x32_bf16(ka1, q1h1, z, 0, 0, 0);
            a0a = __builtin_amdgcn_mfma_f32_16x16x32_bf16(la0, q0h0, a0a, 0, 0, 0);
            a0b = __builtin_amdgcn_mfma_f32_16x16x32_bf16(la1, q0h1, a0b, 0, 0, 0);
            a1a = __builtin_amdgcn_mfma_f32_16x16x32_bf16(la0, q1h0, a1a, 0, 0, 0);
            a1b = __builtin_amdgcn_mfma_f32_16x16x32_bf16(la1, q1h1, a1b, 0, 0, 0);
            a0a = __builtin_amdgcn_mfma_f32_16x16x32_bf16(ka0, q0l0, a0a, 0, 0, 0);
            a0b = __builtin_amdgcn_mfma_f32_16x16x32_bf16(ka1, q0l1, a0b, 0, 0, 0);
            a1a = __builtin_amdgcn_mfma_f32_16x16x32_bf16(ka0, q1l0, a1a, 0, 0, 0);
            a1b = __builtin_amdgcn_mfma_f32_16x16x32_bf16(ka1, q1l1, a1b, 0, 0, 0);
            __builtin_amdgcn_s_setprio(0);
            f32x4_t a0 = a0a + a0b;
            f32x4_t a1 = a1a + a1b;
            const unsigned mu0 = *(const unsigned*)(MT + c * MSTR + 16 * w + 4 * g);
            const unsigned mu1 = *(const unsigned*)(MT + (16 + c) * MSTR + 16 * w + 4 * g);
            bf16x4_t pe0, pe1;
            #pragma unroll
            for (int r = 0; r < 4; ++r) {
                float e0 = ((mu0 >> (8 * r)) & 255u) ? 0.f : __expf(a0[r]);
                float e1 = ((mu1 >> (8 * r)) & 255u) ? 0.f : __expf(a1[r]);
                lsum0 += e0; lsum1 += e1;
                pe0[r] = (__bf16)e0; pe1[r] = (__bf16)e1;
            }
            paE0[i] = pe0;
            paE1[i] = pe1;
        }
    }

    // ---- tail PV: pair 7, V slots 2,3 ----
    {
        const char* VA  = lds + VBASE + 2 * 18432;
        const char* VBs = lds + VBASE + 3 * 18432;
        bf16x8_t pa80 = __builtin_shufflevector(paE0[14], paE0[15], 0, 1, 2, 3, 4, 5, 6, 7);
        bf16x8_t pa81 = __builtin_shufflevector(paE1[14], paE1[15], 0, 1, 2, 3, 4, 5, 6, 7);
        #pragma unroll
        for (int t = 0; t < 4; ++t) {
            bf16x8_t vbf;
            #pragma unroll
            for (int j = 0; j < 4; ++j) {
                const int rr = 16 * w + 4 * g + j;
                vbf[j]     = *(const __bf16*)(VA  + rr * KSTR + (16 * t + c) * 2);
                vbf[4 + j] = *(const __bf16*)(VBs + rr * KSTR + (16 * t + c) * 2);
            }
            of0[t] = __builtin_amdgcn_mfma_f32_16x16x32_bf16(pa80, vbf, of0[t], 0, 0, 0);
            of1[t] = __builtin_amdgcn_mfma_f32_16x16x32_bf16(pa81, vbf, of1[t], 0, 0, 0);
        }
    }

    // =============== epilogue (R11-verified; new overlay bases) ===============
    lsum0 += __shfl_xor(lsum0, 16); lsum0 += __shfl_xor(lsum0, 32);
    lsum1 += __shfl_xor(lsum1, 16); lsum1 += __shfl_xor(lsum1, 32);
    float* Lbuf = (float*)(lds + LBB);
    if (l < 16) {
        Lbuf[w * 32 + l]      = lsum0;
        Lbuf[w * 32 + 16 + l] = lsum1;
    }

    // O partials, m-tile 0, into dead K region
    {
        float* Ow = (float*)(lds + w * 4096);
        #pragma unroll
        for (int t = 0; t < 4; ++t)
            #pragma unroll
            for (int r = 0; r < 4; ++r)
                Ow[(g * 4 + r) * 64 + t * 16 + c] = of0[t][r];
    }
    __syncthreads();

    float* Rinv = (float*)(lds + RIB);
    if (tid < 32) {
        float s = 0.f;
        #pragma unroll
        for (int ww = 0; ww < 8; ++ww) s += Lbuf[ww * 32 + tid];
        Rinv[tid] = 1.0f / s;
    }
    __syncthreads();

    if (tid < 256) {
        const int row = tid >> 4;
        const int dc  = (tid & 15) * 4;
        const float ri = Rinv[row];
        f32x4_t o = {0.f, 0.f, 0.f, 0.f};
        #pragma unroll
        for (int ww = 0; ww < 8; ++ww)
            o += *(const f32x4_t*)((const float*)(lds + ww * 4096) + row * 64 + dc);
        o.x *= ri; o.y *= ri; o.z *= ri; o.w *= ri;
        *(f32x4_t*)(out0 + ((size_t)(b * N_ + m0 + row)) * D_ + dc) = o;
    }
    __syncthreads();

    // O partials, m-tile 1 (reuse region)
    {
        float* Ow = (float*)(lds + w * 4096);
        #pragma unroll
        for (int t = 0; t < 4; ++t)
            #pragma unroll
            for (int r = 0; r < 4; ++r)
                Ow[(g * 4 + r) * 64 + t * 16 + c] = of1[t][r];
    }
    __syncthreads();

    if (tid < 256) {
        const int row = tid >> 4;
        const int dc  = (tid & 15) * 4;
        const float ri = Rinv[16 + row];
        f32x4_t o = {0.f, 0.f, 0.f, 0.f};
        #pragma unroll
        for (int ww = 0; ww < 8; ++ww)
            o += *(const f32x4_t*)((const float*)(lds + ww * 4096) + row * 64 + dc);
        o.x *= ri; o.y *= ri; o.z *= ri; o.w *= ri;
        *(f32x4_t*)(out0 + ((size_t)(b * N_ + m0 + 16 + row)) * D_ + dc) = o;
    }

    // out1: per-wave transpose bounce (Et overlays dead V region), both m-tiles
    {
        char* Et = lds + VBASE + w * 640;               // [16][20] bf16, wave-private
        const int   rm  = l >> 2;
        const int   kq  = l & 3;
        const float ri0 = Rinv[rm];
        const float ri1 = Rinv[16 + rm];
        float* o1r0 = out1 + (size_t)(b * N_ + m0 + rm) * N_;
        float* o1r1 = out1 + (size_t)(b * N_ + m0 + 16 + rm) * N_;
        #pragma unroll
        for (int u = 0; u < 16; ++u) {
            const int n0 = u * 128 + 16 * w;
            *(bf16x4_t*)(Et + c * 40 + g * 8) = paE0[u];
            bf16x4_t er0 = *(const bf16x4_t*)(Et + rm * 40 + kq * 8);
            f32x4_t o40;
            #pragma unroll
            for (int j = 0; j < 4; ++j) o40[j] = (float)er0[j] * ri0;
            *(f32x4_t*)(o1r0 + n0 + kq * 4) = o40;

            *(bf16x4_t*)(Et + c * 40 + g * 8) = paE1[u];
            bf16x4_t er1 = *(const bf16x4_t*)(Et + rm * 40 + kq * 8);
            f32x4_t o41;
            #pragma unroll
            for (int j = 0; j < 4; ++j) o41[j] = (float)er1[j] * ri1;
            *(f32x4_t*)(o1r1 + n0 + kq * 4) = o41;
        }
    }
}

extern "C" void kernel_launch(void* const* d_in, const int* in_sizes, int n_in,
                              void* d_out, int out_size, void* d_ws, size_t ws_size,
                              hipStream_t stream) {
    (void)in_sizes; (void)n_in; (void)out_size; (void)d_ws; (void)ws_size;
    const float* q = (const float*)d_in[0];
    const float* k = (const float*)d_in[1];
    const float* v = (const float*)d_in[2];
    const int* mask = (const int*)d_in[3];
    float* out0 = (float*)d_out;                          // [B,N,D]
    float* out1 = out0 + (size_t)B_ * N_ * D_;            // [B,N,N]
    attn_fused<<<dim3(B_ * (N_ / 32)), dim3(512), 0, stream>>>(q, k, v, mask, out0, out1);
}